// Round 9
// baseline (160.724 us; speedup 1.0000x reference)
//
#include <hip/hip_runtime.h>

#define NN 100000
#define NE 1000000
#define OUT_D 64
#define EPS 1e-5f

#define NB 196          // buckets of 512 destination cols: 196*512 = 100352 >= NN
#define COLS 512
#define BSTRIDE 6016    // per-bucket raw capacity: mean 5120, +12.6 sigma
#define PBSTRIDE 8064   // padded capacity per bucket (mult of 4)
#define HCOLS 256       // place half-bucket width
#define HSTRIDE 4032    // PBSTRIDE/2: padded capacity per half bucket
#define EPB 4096        // edges per part-block
#define NBLK1 245       // part blocks = ceil(NE/EPB)
#define NPROJ 1024      // proj blocks fused behind part

typedef __attribute__((ext_vector_type(8))) short bf16x8;
typedef __attribute__((ext_vector_type(4))) float f32x4;
typedef __attribute__((ext_vector_type(4))) int i32x4;

static __device__ __forceinline__ unsigned short f2bf(float f) {   // RNE
    unsigned u = __float_as_uint(f);
    u += 0x7FFFu + ((u >> 16) & 1u);
    return (unsigned short)(u >> 16);
}
static __device__ __forceinline__ float bf2f(unsigned short s) {
    return __uint_as_float((unsigned)s << 16);
}

// ---- mega kernel: blocks [0,NBLK1) partition edges; [NBLK1,..) do MFMA proj
__global__ __launch_bounds__(256) void mega_kernel(
    const float* __restrict__ x, const float* __restrict__ W,
    const float* __restrict__ bias,
    const int* __restrict__ ei, int* __restrict__ gcur, unsigned* __restrict__ gbuf,
    unsigned short* __restrict__ y1, unsigned short* __restrict__ y2)
{
    const int tid = threadIdx.x;
    const int lane = tid & 63;
    const int wv = tid >> 6;

    if (blockIdx.x < NBLK1) {
        // ---------------- partition by dst-bucket (LDS-staged) ----------------
        __shared__ int lcnt[NB];
        __shared__ int loff[NB + 1];
        __shared__ int lbase[NB];
        __shared__ int lcur[NB];
        __shared__ int wpart[4];
        __shared__ unsigned lbuf[EPB];
        __shared__ unsigned char lbkt[EPB];
        const int e0 = blockIdx.x * EPB;

        int rows[16], cols[16];
        #pragma unroll
        for (int j = 0; j < 16; ++j) {
            const int e = e0 + j * 256 + tid;
            const bool v = e < NE;
            rows[j] = v ? ei[e] : 0;
            cols[j] = v ? ei[NE + e] : -1;
        }
        for (int i = tid; i < NB; i += 256) lcnt[i] = 0;
        __syncthreads();
        #pragma unroll
        for (int j = 0; j < 16; ++j)
            if (cols[j] >= 0) atomicAdd(&lcnt[cols[j] >> 9], 1);
        __syncthreads();
        {   // block exclusive scan over NB bucket counts
            const int c = (tid < NB) ? lcnt[tid] : 0;
            int s = c;
            #pragma unroll
            for (int o = 1; o < 64; o <<= 1) { int t = __shfl_up(s, o); if (lane >= o) s += t; }
            if (lane == 63) wpart[wv] = s;
            __syncthreads();
            int woff = 0;
            for (int ww = 0; ww < wv; ++ww) woff += wpart[ww];
            if (tid < NB) {
                loff[tid] = woff + s - c;
                lcur[tid] = woff + s - c;
                lbase[tid] = atomicAdd(&gcur[tid], c);
            }
            if (tid == NB - 1) loff[NB] = woff + s;
        }
        __syncthreads();
        #pragma unroll
        for (int j = 0; j < 16; ++j) {
            if (cols[j] >= 0) {
                const int b = cols[j] >> 9;
                const int p = atomicAdd(&lcur[b], 1);
                lbuf[p] = ((unsigned)rows[j] << 9) | (unsigned)(cols[j] & (COLS - 1));
                lbkt[p] = (unsigned char)b;
            }
        }
        __syncthreads();
        const int total = loff[NB];
        for (int t = tid; t < total; t += 256) {   // ~21-word coalesced bursts
            const int b = lbkt[t];
            const unsigned idx = (unsigned)(lbase[b] + (t - loff[b]));
            if (idx < BSTRIDE)
                __builtin_nontemporal_store(lbuf[t], &gbuf[(size_t)b * BSTRIDE + idx]);
        }
    } else {
        // ----- [y1|y2] = x @ [W1|W2] via MFMA (m89 layouts); bias folded in y1
        const int m = lane & 15;
        const int quad = lane >> 4;
        bf16x8 Wf[8][2];
        float binit[4];
        #pragma unroll
        for (int t = 0; t < 8; ++t)
            #pragma unroll
            for (int q = 0; q < 2; ++q) {
                bf16x8 f;
                #pragma unroll
                for (int j = 0; j < 8; ++j) {
                    const int k = q * 32 + quad * 8 + j;
                    const int krow = (t < 4) ? k : (64 + k);
                    const int col = (t & 3) * 16 + m;
                    f[j] = (short)f2bf(W[krow * 64 + col]);
                }
                Wf[t][q] = f;
            }
        #pragma unroll
        for (int t = 0; t < 4; ++t) binit[t] = bias[t * 16 + m];
        for (int tile = (blockIdx.x - NBLK1) * 4 + wv; tile < NN / 16; tile += NPROJ * 4) {
            const int n0 = tile * 16;
            bf16x8 Af[2];
            #pragma unroll
            for (int q = 0; q < 2; ++q) {
                const float* px = x + (size_t)(n0 + m) * 64 + q * 32 + quad * 8;
                const f32x4 a0 = *(const f32x4*)px;
                const f32x4 a1 = *(const f32x4*)(px + 4);
                bf16x8 f;
                #pragma unroll
                for (int j = 0; j < 4; ++j) { f[j] = (short)f2bf(a0[j]); f[4 + j] = (short)f2bf(a1[j]); }
                Af[q] = f;
            }
            #pragma unroll
            for (int t = 0; t < 8; ++t) {
                const float ini = (t < 4) ? binit[t] : 0.f;
                f32x4 acc = {ini, ini, ini, ini};
                acc = __builtin_amdgcn_mfma_f32_16x16x32_bf16(Af[0], Wf[t][0], acc, 0, 0, 0);
                acc = __builtin_amdgcn_mfma_f32_16x16x32_bf16(Af[1], Wf[t][1], acc, 0, 0, 0);
                unsigned short* __restrict__ dst = (t < 4) ? y1 : y2;
                const int colb = (t & 3) * 16 + m;
                #pragma unroll
                for (int r = 0; r < 4; ++r)
                    __builtin_nontemporal_store(f2bf(acc[r]),
                        &dst[(size_t)(n0 + quad * 4 + r) * 64 + colb]);
            }
        }
    }
}

// ---- per-HALF-bucket padded CSR build: segments 4-aligned, pads -> row NN --
__global__ __launch_bounds__(256) void place_kernel(
    const int* __restrict__ gcur, const unsigned* __restrict__ gbuf,
    int* __restrict__ csr, unsigned* __restrict__ rowpack,
    unsigned short* __restrict__ y2)
{
    __shared__ int cofs[HCOLS + 1];  // padded exclusive scan (+ total at end)
    __shared__ int ccur[HCOLS];
    __shared__ int ldst[HSTRIDE];
    const int b = blockIdx.x >> 1;       // bucket
    const int h = blockIdx.x & 1;        // half
    const int tid = threadIdx.x;
    const int qlo = h * HCOLS;
    const int n0 = (b << 9) + qlo;

    if (blockIdx.x == 0 && tid < 64) y2[(size_t)NN * OUT_D + tid] = 0;  // zeros row

    for (int i = tid; i < HCOLS; i += 256) cofs[i] = 0;
    for (int i = tid; i < HSTRIDE; i += 256) ldst[i] = NN;              // pad rows
    __syncthreads();
    const int cntE = min(gcur[b], BSTRIDE);
    const unsigned* __restrict__ gb = gbuf + (size_t)b * BSTRIDE;

    for (int i = tid; i < cntE; i += 256) {    // histogram my 256 cols
        const int c = (int)(gb[i] & (COLS - 1)) - qlo;
        if ((unsigned)c < HCOLS) atomicAdd(&cofs[c], 1);
    }
    __syncthreads();
    if (tid < 64) {   // single-wave exclusive scan of 256 PADDED counts (4/lane)
        int v[4], tsum = 0;
        #pragma unroll
        for (int k = 0; k < 4; ++k) { v[k] = (cofs[tid * 4 + k] + 3) & ~3; tsum += v[k]; }
        int s = tsum;
        #pragma unroll
        for (int o = 1; o < 64; o <<= 1) { int t = __shfl_up(s, o); if (tid >= o) s += t; }
        int run = s - tsum;
        #pragma unroll
        for (int k = 0; k < 4; ++k) { cofs[tid * 4 + k] = run; ccur[tid * 4 + k] = run; run += v[k]; }
        if (tid == 63) cofs[HCOLS] = run;
    }
    __syncthreads();
    for (int i = tid; i < cntE; i += 256) {    // place rows (LDS scatter)
        const unsigned p = gb[i];
        const int c = (int)(p & (COLS - 1)) - qlo;
        if ((unsigned)c < HCOLS) {
            const int pos = atomicAdd(&ccur[c], 1);
            if (pos < HSTRIDE) ldst[pos] = (int)(p >> 9);
        }
    }
    __syncthreads();
    const int ptotal = min(cofs[HCOLS], HSTRIDE);
    const int base = b * PBSTRIDE + h * HSTRIDE;
    for (int i = tid; i < ptotal; i += 256)
        __builtin_nontemporal_store(ldst[i], &csr[base + i]);   // coalesced
    const int ncols = min(HCOLS, NN - n0);
    for (int c = tid; c < ncols; c += 256) {
        const int st = h * HSTRIDE + min(cofs[c], HSTRIDE);     // 13 bits
        const int len = min(cofs[c + 1] - cofs[c], 511);
        __builtin_nontemporal_store(((unsigned)st << 9) | (unsigned)len, &rowpack[n0 + c]);
    }
}

// ---- out: one node per wave; padded csr (scalar dwordx4), 8 gathers deep ---
__global__ __launch_bounds__(256) void out_kernel(
    const unsigned* __restrict__ rowpack, const int* __restrict__ csr,
    const unsigned short* __restrict__ y1, const unsigned short* __restrict__ y2,
    const float* __restrict__ gamma, const float* __restrict__ beta,
    float* __restrict__ out)
{
    const int lane = threadIdx.x & 63;
    const int n = __builtin_amdgcn_readfirstlane(blockIdx.x * 4 + (threadIdx.x >> 6));
    const unsigned pk = rowpack[n];
    const int cnt = (int)(pk & 511);                       // multiple of 4
    const i32x4* __restrict__ cs =
        (const i32x4*)(csr + (n >> 9) * PBSTRIDE + (int)(pk >> 9));

    float acc = bf2f(__builtin_nontemporal_load(&y1[(size_t)n * OUT_D + lane]));  // bias inside
    int i = 0;
    for (; i + 8 <= cnt; i += 8) {                         // 8 gathers in flight
        const i32x4 c0 = cs[(i >> 2)];
        const i32x4 c1 = cs[(i >> 2) + 1];
        const float v0 = bf2f(y2[(size_t)c0[0] * OUT_D + lane]);
        const float v1 = bf2f(y2[(size_t)c0[1] * OUT_D + lane]);
        const float v2 = bf2f(y2[(size_t)c0[2] * OUT_D + lane]);
        const float v3 = bf2f(y2[(size_t)c0[3] * OUT_D + lane]);
        const float v4 = bf2f(y2[(size_t)c1[0] * OUT_D + lane]);
        const float v5 = bf2f(y2[(size_t)c1[1] * OUT_D + lane]);
        const float v6 = bf2f(y2[(size_t)c1[2] * OUT_D + lane]);
        const float v7 = bf2f(y2[(size_t)c1[3] * OUT_D + lane]);
        acc += ((v0 + v1) + (v2 + v3)) + ((v4 + v5) + (v6 + v7));
    }
    if (i < cnt) {                                         // exactly 4 left
        const i32x4 c0 = cs[(i >> 2)];
        const float v0 = bf2f(y2[(size_t)c0[0] * OUT_D + lane]);
        const float v1 = bf2f(y2[(size_t)c0[1] * OUT_D + lane]);
        const float v2 = bf2f(y2[(size_t)c0[2] * OUT_D + lane]);
        const float v3 = bf2f(y2[(size_t)c0[3] * OUT_D + lane]);
        acc += (v0 + v1) + (v2 + v3);
    }

    float sv = acc, sq = acc * acc;
    #pragma unroll
    for (int off = 32; off; off >>= 1) { sv += __shfl_xor(sv, off); sq += __shfl_xor(sq, off); }
    const float mu  = sv * (1.0f / OUT_D);
    const float var = sq * (1.0f / OUT_D) - mu * mu;
    const float inv = rsqrtf(var + EPS);
    __builtin_nontemporal_store((acc - mu) * inv * gamma[lane] + beta[lane],
                                &out[(size_t)n * OUT_D + lane]);
}

extern "C" void kernel_launch(void* const* d_in, const int* in_sizes, int n_in,
                              void* d_out, int out_size, void* d_ws, size_t ws_size,
                              hipStream_t stream) {
    const float* x     = (const float*)d_in[0];
    const int*   ei    = (const int*)  d_in[1];
    const float* W     = (const float*)d_in[2];
    const float* b     = (const float*)d_in[3];
    const float* gamma = (const float*)d_in[4];
    const float* beta  = (const float*)d_in[5];
    float* out = (float*)d_out;

    char* p = (char*)d_ws;
    int*            gcur    = (int*)p;             p += 1024;
    unsigned*       gbuf    = (unsigned*)p;        p += (size_t)NB * BSTRIDE * 4;   // 4.72 MB
    int*            csr     = (int*)p;             p += (size_t)NB * PBSTRIDE * 4;  // 6.32 MB
    unsigned*       rowpack = (unsigned*)p;        p += (size_t)(NB * COLS) * 4;    // 0.4 MB
    unsigned short* y1      = (unsigned short*)p;  p += (size_t)NN * OUT_D * 2;     // 12.8 MB
    unsigned short* y2      = (unsigned short*)p;                                   // 12.8 MB + pad row

    hipMemsetAsync(gcur, 0, NB * sizeof(int), stream);
    mega_kernel <<<NBLK1 + NPROJ, 256, 0, stream>>>(x, W, b, ei, gcur, gbuf, y1, y2);
    place_kernel<<<NB * 2, 256, 0, stream>>>(gcur, gbuf, csr, rowpack, y2);
    out_kernel  <<<NN / 4, 256, 0, stream>>>(rowpack, csr, y1, y2, gamma, beta, out);
}

// Round 10
// 146.436 us; speedup vs baseline: 1.0976x; 1.0976x over previous
//
#include <hip/hip_runtime.h>

#define NN 100000
#define NE 1000000
#define OUT_D 64
#define EPS 1e-5f

#define NB 196          // buckets of 512 destination cols: 196*512 = 100352 >= NN
#define COLS 512
#define BSTRIDE 6016    // per-bucket raw capacity: mean 5120, +12.6 sigma
#define PBSTRIDE 8064   // padded capacity per bucket (mult of 4)
#define HCOLS 256       // place half-bucket width
#define HSTRIDE 4032    // PBSTRIDE/2: padded capacity per half bucket
#define EPB 4096        // edges per part-block
#define NBLK1 245       // part blocks = ceil(NE/EPB)
#define NPROJ 1024      // proj blocks fused behind part

typedef __attribute__((ext_vector_type(8))) short bf16x8;
typedef __attribute__((ext_vector_type(4))) float f32x4;
typedef __attribute__((ext_vector_type(4))) int i32x4;

static __device__ __forceinline__ unsigned short f2bf(float f) {   // RNE
    unsigned u = __float_as_uint(f);
    u += 0x7FFFu + ((u >> 16) & 1u);
    return (unsigned short)(u >> 16);
}
static __device__ __forceinline__ float bf2f(unsigned short s) {
    return __uint_as_float((unsigned)s << 16);
}

// ---- mega kernel: blocks [0,NBLK1) partition edges; [NBLK1,..) do MFMA proj
__global__ __launch_bounds__(256) void mega_kernel(
    const float* __restrict__ x, const float* __restrict__ W,
    const float* __restrict__ bias,
    const int* __restrict__ ei, int* __restrict__ gcur, unsigned* __restrict__ gbuf,
    unsigned short* __restrict__ y1, unsigned short* __restrict__ y2)
{
    const int tid = threadIdx.x;
    const int lane = tid & 63;
    const int wv = tid >> 6;

    if (blockIdx.x < NBLK1) {
        // ---------------- partition by dst-bucket (LDS-staged) ----------------
        __shared__ int lcnt[NB];
        __shared__ int loff[NB + 1];
        __shared__ int lbase[NB];
        __shared__ int lcur[NB];
        __shared__ int wpart[4];
        __shared__ unsigned lbuf[EPB];
        __shared__ unsigned char lbkt[EPB];
        const int e0 = blockIdx.x * EPB;

        int rows[16], cols[16];
        #pragma unroll
        for (int j = 0; j < 16; ++j) {
            const int e = e0 + j * 256 + tid;
            const bool v = e < NE;
            rows[j] = v ? ei[e] : 0;
            cols[j] = v ? ei[NE + e] : -1;
        }
        for (int i = tid; i < NB; i += 256) lcnt[i] = 0;
        __syncthreads();
        #pragma unroll
        for (int j = 0; j < 16; ++j)
            if (cols[j] >= 0) atomicAdd(&lcnt[cols[j] >> 9], 1);
        __syncthreads();
        {   // block exclusive scan over NB bucket counts
            const int c = (tid < NB) ? lcnt[tid] : 0;
            int s = c;
            #pragma unroll
            for (int o = 1; o < 64; o <<= 1) { int t = __shfl_up(s, o); if (lane >= o) s += t; }
            if (lane == 63) wpart[wv] = s;
            __syncthreads();
            int woff = 0;
            for (int ww = 0; ww < wv; ++ww) woff += wpart[ww];
            if (tid < NB) {
                loff[tid] = woff + s - c;
                lcur[tid] = woff + s - c;
                lbase[tid] = atomicAdd(&gcur[tid], c);
            }
            if (tid == NB - 1) loff[NB] = woff + s;
        }
        __syncthreads();
        #pragma unroll
        for (int j = 0; j < 16; ++j) {
            if (cols[j] >= 0) {
                const int b = cols[j] >> 9;
                const int p = atomicAdd(&lcur[b], 1);
                lbuf[p] = ((unsigned)rows[j] << 9) | (unsigned)(cols[j] & (COLS - 1));
                lbkt[p] = (unsigned char)b;
            }
        }
        __syncthreads();
        const int total = loff[NB];
        for (int t = tid; t < total; t += 256) {   // ~21-word coalesced bursts
            const int b = lbkt[t];
            const unsigned idx = (unsigned)(lbase[b] + (t - loff[b]));
            if (idx < BSTRIDE) gbuf[(size_t)b * BSTRIDE + idx] = lbuf[t];
        }
    } else {
        // ----- [y1|y2] = x @ [W1|W2] via MFMA (m89 layouts); bias folded in y1
        const int m = lane & 15;
        const int quad = lane >> 4;
        bf16x8 Wf[8][2];
        float binit[4];
        #pragma unroll
        for (int t = 0; t < 8; ++t)
            #pragma unroll
            for (int q = 0; q < 2; ++q) {
                bf16x8 f;
                #pragma unroll
                for (int j = 0; j < 8; ++j) {
                    const int k = q * 32 + quad * 8 + j;
                    const int krow = (t < 4) ? k : (64 + k);
                    const int col = (t & 3) * 16 + m;
                    f[j] = (short)f2bf(W[krow * 64 + col]);
                }
                Wf[t][q] = f;
            }
        #pragma unroll
        for (int t = 0; t < 4; ++t) binit[t] = bias[t * 16 + m];
        for (int tile = (blockIdx.x - NBLK1) * 4 + wv; tile < NN / 16; tile += NPROJ * 4) {
            const int n0 = tile * 16;
            bf16x8 Af[2];
            #pragma unroll
            for (int q = 0; q < 2; ++q) {
                const float* px = x + (size_t)(n0 + m) * 64 + q * 32 + quad * 8;
                const f32x4 a0 = *(const f32x4*)px;
                const f32x4 a1 = *(const f32x4*)(px + 4);
                bf16x8 f;
                #pragma unroll
                for (int j = 0; j < 4; ++j) { f[j] = (short)f2bf(a0[j]); f[4 + j] = (short)f2bf(a1[j]); }
                Af[q] = f;
            }
            #pragma unroll
            for (int t = 0; t < 8; ++t) {
                const float ini = (t < 4) ? binit[t] : 0.f;
                f32x4 acc = {ini, ini, ini, ini};
                acc = __builtin_amdgcn_mfma_f32_16x16x32_bf16(Af[0], Wf[t][0], acc, 0, 0, 0);
                acc = __builtin_amdgcn_mfma_f32_16x16x32_bf16(Af[1], Wf[t][1], acc, 0, 0, 0);
                unsigned short* __restrict__ dst = (t < 4) ? y1 : y2;
                const int colb = (t & 3) * 16 + m;
                #pragma unroll
                for (int r = 0; r < 4; ++r)
                    dst[(size_t)(n0 + quad * 4 + r) * 64 + colb] = f2bf(acc[r]);
            }
        }
    }
}

// ---- per-HALF-bucket padded CSR build: segments 4-aligned, pads -> row NN --
__global__ __launch_bounds__(256) void place_kernel(
    const int* __restrict__ gcur, const unsigned* __restrict__ gbuf,
    int* __restrict__ csr, unsigned* __restrict__ rowpack,
    unsigned short* __restrict__ y2)
{
    __shared__ int cofs[HCOLS + 1];  // padded exclusive scan (+ total at end)
    __shared__ int ccur[HCOLS];
    __shared__ int ldst[HSTRIDE];
    const int b = blockIdx.x >> 1;       // bucket
    const int h = blockIdx.x & 1;        // half
    const int tid = threadIdx.x;
    const int qlo = h * HCOLS;
    const int n0 = (b << 9) + qlo;

    if (blockIdx.x == 0 && tid < 64) y2[(size_t)NN * OUT_D + tid] = 0;  // zeros row

    for (int i = tid; i < HCOLS; i += 256) cofs[i] = 0;
    for (int i = tid; i < HSTRIDE; i += 256) ldst[i] = NN;              // pad rows
    __syncthreads();
    const int cntE = min(gcur[b], BSTRIDE);
    const unsigned* __restrict__ gb = gbuf + (size_t)b * BSTRIDE;

    for (int i = tid; i < cntE; i += 256) {    // histogram my 256 cols
        const int c = (int)(gb[i] & (COLS - 1)) - qlo;
        if ((unsigned)c < HCOLS) atomicAdd(&cofs[c], 1);
    }
    __syncthreads();
    if (tid < 64) {   // single-wave exclusive scan of 256 PADDED counts (4/lane)
        int v[4], tsum = 0;
        #pragma unroll
        for (int k = 0; k < 4; ++k) { v[k] = (cofs[tid * 4 + k] + 3) & ~3; tsum += v[k]; }
        int s = tsum;
        #pragma unroll
        for (int o = 1; o < 64; o <<= 1) { int t = __shfl_up(s, o); if (tid >= o) s += t; }
        int run = s - tsum;
        #pragma unroll
        for (int k = 0; k < 4; ++k) { cofs[tid * 4 + k] = run; ccur[tid * 4 + k] = run; run += v[k]; }
        if (tid == 63) cofs[HCOLS] = run;
    }
    __syncthreads();
    for (int i = tid; i < cntE; i += 256) {    // place rows (LDS scatter)
        const unsigned p = gb[i];
        const int c = (int)(p & (COLS - 1)) - qlo;
        if ((unsigned)c < HCOLS) {
            const int pos = atomicAdd(&ccur[c], 1);
            if (pos < HSTRIDE) ldst[pos] = (int)(p >> 9);
        }
    }
    __syncthreads();
    const int ptotal = min(cofs[HCOLS], HSTRIDE);
    const int base = b * PBSTRIDE + h * HSTRIDE;
    for (int i = tid; i < ptotal; i += 256) csr[base + i] = ldst[i];    // coalesced
    const int ncols = min(HCOLS, NN - n0);
    for (int c = tid; c < ncols; c += 256) {
        const int st = h * HSTRIDE + min(cofs[c], HSTRIDE);             // 13 bits
        const int len = min(cofs[c + 1] - cofs[c], 511);
        rowpack[n0 + c] = ((unsigned)st << 9) | (unsigned)len;
    }
}

// ---- out: one node per wave; padded csr (scalar dwordx4), 8 gathers deep ---
__global__ __launch_bounds__(256) void out_kernel(
    const unsigned* __restrict__ rowpack, const int* __restrict__ csr,
    const unsigned short* __restrict__ y1, const unsigned short* __restrict__ y2,
    const float* __restrict__ gamma, const float* __restrict__ beta,
    float* __restrict__ out)
{
    const int lane = threadIdx.x & 63;
    const int n = __builtin_amdgcn_readfirstlane(blockIdx.x * 4 + (threadIdx.x >> 6));
    const unsigned pk = rowpack[n];
    const int cnt = (int)(pk & 511);                       // multiple of 4
    const i32x4* __restrict__ cs =
        (const i32x4*)(csr + (n >> 9) * PBSTRIDE + (int)(pk >> 9));

    float acc = bf2f(y1[(size_t)n * OUT_D + lane]);        // bias already folded in
    int i = 0;
    for (; i + 8 <= cnt; i += 8) {                         // 8 gathers in flight
        const i32x4 c0 = cs[(i >> 2)];
        const i32x4 c1 = cs[(i >> 2) + 1];
        const float v0 = bf2f(y2[(size_t)c0[0] * OUT_D + lane]);
        const float v1 = bf2f(y2[(size_t)c0[1] * OUT_D + lane]);
        const float v2 = bf2f(y2[(size_t)c0[2] * OUT_D + lane]);
        const float v3 = bf2f(y2[(size_t)c0[3] * OUT_D + lane]);
        const float v4 = bf2f(y2[(size_t)c1[0] * OUT_D + lane]);
        const float v5 = bf2f(y2[(size_t)c1[1] * OUT_D + lane]);
        const float v6 = bf2f(y2[(size_t)c1[2] * OUT_D + lane]);
        const float v7 = bf2f(y2[(size_t)c1[3] * OUT_D + lane]);
        acc += ((v0 + v1) + (v2 + v3)) + ((v4 + v5) + (v6 + v7));
    }
    if (i < cnt) {                                         // exactly 4 left
        const i32x4 c0 = cs[(i >> 2)];
        const float v0 = bf2f(y2[(size_t)c0[0] * OUT_D + lane]);
        const float v1 = bf2f(y2[(size_t)c0[1] * OUT_D + lane]);
        const float v2 = bf2f(y2[(size_t)c0[2] * OUT_D + lane]);
        const float v3 = bf2f(y2[(size_t)c0[3] * OUT_D + lane]);
        acc += (v0 + v1) + (v2 + v3);
    }

    float sv = acc, sq = acc * acc;
    #pragma unroll
    for (int off = 32; off; off >>= 1) { sv += __shfl_xor(sv, off); sq += __shfl_xor(sq, off); }
    const float mu  = sv * (1.0f / OUT_D);
    const float var = sq * (1.0f / OUT_D) - mu * mu;
    const float inv = rsqrtf(var + EPS);
    out[(size_t)n * OUT_D + lane] = (acc - mu) * inv * gamma[lane] + beta[lane];
}

extern "C" void kernel_launch(void* const* d_in, const int* in_sizes, int n_in,
                              void* d_out, int out_size, void* d_ws, size_t ws_size,
                              hipStream_t stream) {
    const float* x     = (const float*)d_in[0];
    const int*   ei    = (const int*)  d_in[1];
    const float* W     = (const float*)d_in[2];
    const float* b     = (const float*)d_in[3];
    const float* gamma = (const float*)d_in[4];
    const float* beta  = (const float*)d_in[5];
    float* out = (float*)d_out;

    char* p = (char*)d_ws;
    int*            gcur    = (int*)p;             p += 1024;
    unsigned*       gbuf    = (unsigned*)p;        p += (size_t)NB * BSTRIDE * 4;   // 4.72 MB
    int*            csr     = (int*)p;             p += (size_t)NB * PBSTRIDE * 4;  // 6.32 MB
    unsigned*       rowpack = (unsigned*)p;        p += (size_t)(NB * COLS) * 4;    // 0.4 MB
    unsigned short* y1      = (unsigned short*)p;  p += (size_t)NN * OUT_D * 2;     // 12.8 MB
    unsigned short* y2      = (unsigned short*)p;                                   // 12.8 MB + pad row

    hipMemsetAsync(gcur, 0, NB * sizeof(int), stream);
    mega_kernel <<<NBLK1 + NPROJ, 256, 0, stream>>>(x, W, b, ei, gcur, gbuf, y1, y2);
    place_kernel<<<NB * 2, 256, 0, stream>>>(gcur, gbuf, csr, rowpack, y2);
    out_kernel  <<<NN / 4, 256, 0, stream>>>(rowpack, csr, y1, y2, gamma, beta, out);
}